// Round 1
// baseline (122.354 us; speedup 1.0000x reference)
//
#include <hip/hip_runtime.h>
#include <hip/hip_bf16.h>

// UVCrossAttention — MI355X (gfx950)
//
// Shapes (fixed by setup_inputs): bsv=1, nq=nv=1024 (32x32), E=D=128,
// CAMS=HEADS=LEVELS=1, P=4.
//
// Key algebraic trick: bilinear sampling is linear in the image, and the
// sampled 128-vec is immediately dotted with key2[q]. So precompute
//   dotv[q][v] = (value[v] @ W_v + b_v) . key[q]      (1024x1024 fp32, 4 MB)
// and sample SCALARS from dotv[q][.] as a 32x32 image instead of gathering
// 128-wide vectors. One dotv row (4 KB) fits in LDS per query.

#define NQ   1024
#define NV   1024
#define E    128
#define ND   128
#define NP   4
#define IMG_W 32
#define IMG_H 32

// ---------------------------------------------------------------------------
// NN GEMM: C[M,N] = A[M,128] @ B[128,N] (+bias[N]) (+add[M,N])
// 64x64 tile, 256 threads, 4x4 micro-tile, K=128 fully staged.
// ---------------------------------------------------------------------------
__global__ __launch_bounds__(256) void gemm_nn_k128(
    const float* __restrict__ A, const float* __restrict__ B,
    const float* __restrict__ bias, const float* __restrict__ add,
    float* __restrict__ C, int M, int N) {
  __shared__ float As[64][129];   // pad 129: conflict-free scalar reads
  __shared__ float Bs[128][64];   // float4 reads along n (2-way, free)

  const int tid = threadIdx.x;
  const int tx = tid & 15, ty = tid >> 4;
  const int n0 = blockIdx.x * 64, m0 = blockIdx.y * 64;

  // stage A tile (64 x 128), coalesced float4 global reads
  for (int k = 0; k < 8; ++k) {
    int c = tid + k * 256;        // 0..2047 float4 chunks
    int r = c >> 5;               // row 0..63
    int e4 = c & 31;              // float4 col 0..31
    const float4 v = *(const float4*)(A + (size_t)(m0 + r) * 128 + e4 * 4);
    As[r][e4 * 4 + 0] = v.x; As[r][e4 * 4 + 1] = v.y;
    As[r][e4 * 4 + 2] = v.z; As[r][e4 * 4 + 3] = v.w;
  }
  // stage B tile (128 x 64)
  for (int k = 0; k < 8; ++k) {
    int c = tid + k * 256;
    int e = c >> 4;               // row 0..127
    int n4 = c & 15;
    *(float4*)(&Bs[e][n4 * 4]) = *(const float4*)(B + (size_t)e * N + n0 + n4 * 4);
  }
  __syncthreads();

  float acc[4][4] = {};
#pragma unroll 8
  for (int e = 0; e < 128; ++e) {
    const float a0 = As[ty * 4 + 0][e];
    const float a1 = As[ty * 4 + 1][e];
    const float a2 = As[ty * 4 + 2][e];
    const float a3 = As[ty * 4 + 3][e];
    const float4 b = *(const float4*)(&Bs[e][tx * 4]);
    acc[0][0] += a0 * b.x; acc[0][1] += a0 * b.y; acc[0][2] += a0 * b.z; acc[0][3] += a0 * b.w;
    acc[1][0] += a1 * b.x; acc[1][1] += a1 * b.y; acc[1][2] += a1 * b.z; acc[1][3] += a1 * b.w;
    acc[2][0] += a2 * b.x; acc[2][1] += a2 * b.y; acc[2][2] += a2 * b.z; acc[2][3] += a2 * b.w;
    acc[3][0] += a3 * b.x; acc[3][1] += a3 * b.y; acc[3][2] += a3 * b.z; acc[3][3] += a3 * b.w;
  }

#pragma unroll
  for (int i = 0; i < 4; ++i) {
    const int m = m0 + ty * 4 + i;
    const int n = n0 + tx * 4;
    float4 r;
    r.x = acc[i][0]; r.y = acc[i][1]; r.z = acc[i][2]; r.w = acc[i][3];
    if (bias) {
      r.x += bias[n + 0]; r.y += bias[n + 1]; r.z += bias[n + 2]; r.w += bias[n + 3];
    }
    if (add) {
      const float4 ad = *(const float4*)(add + (size_t)m * N + n);
      r.x += ad.x; r.y += ad.y; r.z += ad.z; r.w += ad.w;
    }
    *(float4*)(C + (size_t)m * N + n) = r;
  }
}

// ---------------------------------------------------------------------------
// NT GEMM: C[M,N] = A[M,128] @ Bt[N,128]^T   (dotv = key @ val2^T)
// ---------------------------------------------------------------------------
__global__ __launch_bounds__(256) void gemm_nt_k128(
    const float* __restrict__ A, const float* __restrict__ Bt,
    float* __restrict__ C, int M, int N) {
  __shared__ float As[64][129];
  __shared__ float Bs[64][129];

  const int tid = threadIdx.x;
  const int tx = tid & 15, ty = tid >> 4;
  const int n0 = blockIdx.x * 64, m0 = blockIdx.y * 64;

  for (int k = 0; k < 8; ++k) {
    int c = tid + k * 256;
    int r = c >> 5;
    int e4 = c & 31;
    const float4 va = *(const float4*)(A + (size_t)(m0 + r) * 128 + e4 * 4);
    As[r][e4 * 4 + 0] = va.x; As[r][e4 * 4 + 1] = va.y;
    As[r][e4 * 4 + 2] = va.z; As[r][e4 * 4 + 3] = va.w;
    const float4 vb = *(const float4*)(Bt + (size_t)(n0 + r) * 128 + e4 * 4);
    Bs[r][e4 * 4 + 0] = vb.x; Bs[r][e4 * 4 + 1] = vb.y;
    Bs[r][e4 * 4 + 2] = vb.z; Bs[r][e4 * 4 + 3] = vb.w;
  }
  __syncthreads();

  float acc[4][4] = {};
#pragma unroll 8
  for (int e = 0; e < 128; ++e) {
    const float a0 = As[ty * 4 + 0][e];
    const float a1 = As[ty * 4 + 1][e];
    const float a2 = As[ty * 4 + 2][e];
    const float a3 = As[ty * 4 + 3][e];
    const float b0 = Bs[tx * 4 + 0][e];
    const float b1 = Bs[tx * 4 + 1][e];
    const float b2 = Bs[tx * 4 + 2][e];
    const float b3 = Bs[tx * 4 + 3][e];
    acc[0][0] += a0 * b0; acc[0][1] += a0 * b1; acc[0][2] += a0 * b2; acc[0][3] += a0 * b3;
    acc[1][0] += a1 * b0; acc[1][1] += a1 * b1; acc[1][2] += a1 * b2; acc[1][3] += a1 * b3;
    acc[2][0] += a2 * b0; acc[2][1] += a2 * b1; acc[2][2] += a2 * b2; acc[2][3] += a2 * b3;
    acc[3][0] += a3 * b0; acc[3][1] += a3 * b1; acc[3][2] += a3 * b2; acc[3][3] += a3 * b3;
  }

#pragma unroll
  for (int i = 0; i < 4; ++i) {
    const int m = m0 + ty * 4 + i;
    const int n = n0 + tx * 4;
    float4 r;
    r.x = acc[i][0]; r.y = acc[i][1]; r.z = acc[i][2]; r.w = acc[i][3];
    *(float4*)(C + (size_t)m * N + n) = r;
  }
}

// ---------------------------------------------------------------------------
// Sampler: per (q,d): softmax over 4 points, 4 bilinear scalar samples from
// dotv[q][.] (32x32 image, staged in LDS), weighted sum, /128.
// Block = 256 threads = 2 queries x 128 depths.
// ---------------------------------------------------------------------------
__global__ __launch_bounds__(256) void sample_kernel(
    const float* __restrict__ dotv,    // [NQ][NV]
    const float* __restrict__ off,     // [NQ][1024]  (d*8 + p*2 + {x,y})
    const float* __restrict__ awr,     // [NQ][512]   raw (d*4 + p)
    const float* __restrict__ ref3d,   // [NQ*ND][2]
    float* __restrict__ out1) {        // [NQ][ND]
  __shared__ float img[2][NV];

  const int tid = threadIdx.x;
  const int q0 = blockIdx.x * 2;

  // stage two dotv rows (2 x 4 KB)
  for (int k = 0; k < 2; ++k) {
    int c = tid + k * 256;        // 0..511 float4 chunks
    int qq = c >> 8;
    int v4 = c & 255;
    *(float4*)(&img[qq][v4 * 4]) =
        *(const float4*)(dotv + (size_t)(q0 + qq) * NV + v4 * 4);
  }
  __syncthreads();

  const int qq = tid >> 7;
  const int q = q0 + qq;
  const int d = tid & 127;
  const float* im = img[qq];
  const size_t qe = (size_t)q * ND + d;

  const float rx = ref3d[qe * 2 + 0];
  const float ry = ref3d[qe * 2 + 1];

  // softmax over the 4 points
  const float* awp = awr + (size_t)q * (ND * NP) + d * NP;
  const float a0 = awp[0], a1 = awp[1], a2 = awp[2], a3 = awp[3];
  const float mx = fmaxf(fmaxf(a0, a1), fmaxf(a2, a3));
  const float e0 = __expf(a0 - mx), e1 = __expf(a1 - mx),
              e2 = __expf(a2 - mx), e3 = __expf(a3 - mx);
  const float inv = 1.0f / (e0 + e1 + e2 + e3);
  float w[4] = {e0 * inv, e1 * inv, e2 * inv, e3 * inv};

  const float* op = off + (size_t)q * (ND * NP * 2) + d * (NP * 2);

  float acc = 0.0f;
#pragma unroll
  for (int p = 0; p < NP; ++p) {
    const float x = rx * (float)IMG_W + op[p * 2 + 0] - 0.5f;
    const float y = ry * (float)IMG_H + op[p * 2 + 1] - 0.5f;
    const float xf = floorf(x), yf = floorf(y);
    const int ix0 = (int)xf, iy0 = (int)yf;
    const float wx1 = x - xf, wy1 = y - yf;
    const float wx0 = 1.0f - wx1, wy0 = 1.0f - wy1;

    float s = 0.0f;
#pragma unroll
    for (int cy = 0; cy < 2; ++cy) {
#pragma unroll
      for (int cx = 0; cx < 2; ++cx) {
        const int ix = ix0 + cx, iy = iy0 + cy;
        const bool valid = (ix >= 0) & (ix < IMG_W) & (iy >= 0) & (iy < IMG_H);
        const int cix = min(max(ix, 0), IMG_W - 1);
        const int ciy = min(max(iy, 0), IMG_H - 1);
        const float wgt = (cx ? wx1 : wx0) * (cy ? wy1 : wy0);
        s += valid ? im[ciy * IMG_W + cix] * wgt : 0.0f;
      }
    }
    acc += w[p] * s;
  }
  out1[qe] = acc * (1.0f / (float)E);
}

// ---------------------------------------------------------------------------
extern "C" void kernel_launch(void* const* d_in, const int* in_sizes, int n_in,
                              void* d_out, int out_size, void* d_ws, size_t ws_size,
                              hipStream_t stream) {
  const float* query  = (const float*)d_in[0];   // [1,1024,128]
  const float* key    = (const float*)d_in[1];   // [1,1024,1,128] -> [1024,128]
  const float* value  = (const float*)d_in[2];   // [1,1024,1,128] -> [1024,128]
  const float* ref3d  = (const float*)d_in[3];   // [1,131072,2]
  // d_in[4] = spatial_shapes [[32,32]] (hardcoded)
  const float* W_off  = (const float*)d_in[5];   // [128,1024]
  const float* b_off  = (const float*)d_in[6];   // [1024]
  const float* W_attn = (const float*)d_in[7];   // [128,512]
  const float* b_attn = (const float*)d_in[8];   // [512]
  const float* W_v    = (const float*)d_in[9];   // [128,128]
  const float* b_v    = (const float*)d_in[10];  // [128]
  const float* W_o    = (const float*)d_in[11];  // [128,128]
  const float* b_o    = (const float*)d_in[12];  // [128]
  float* out = (float*)d_out;                    // [1,1024,128]

  float* ws = (float*)d_ws;
  float* off_out = ws;                           // 1024*1024
  float* aw_out  = off_out + (size_t)NQ * 1024;  // 1024*512
  float* val2    = aw_out + (size_t)NQ * 512;    // 1024*128
  float* dotv    = val2 + (size_t)NV * E;        // 1024*1024
  float* out1    = dotv + (size_t)NQ * NV;       // 1024*128

  // 1) off_out = query @ W_off + b_off            [1024,1024]
  gemm_nn_k128<<<dim3(1024 / 64, NQ / 64), 256, 0, stream>>>(
      query, W_off, b_off, nullptr, off_out, NQ, 1024);
  // 2) aw_out = query @ W_attn + b_attn           [1024,512]
  gemm_nn_k128<<<dim3(512 / 64, NQ / 64), 256, 0, stream>>>(
      query, W_attn, b_attn, nullptr, aw_out, NQ, 512);
  // 3) val2 = value @ W_v + b_v                   [1024,128]
  gemm_nn_k128<<<dim3(128 / 64, NV / 64), 256, 0, stream>>>(
      value, W_v, b_v, nullptr, val2, NV, 128);
  // 4) dotv = key @ val2^T                        [1024,1024]
  gemm_nt_k128<<<dim3(NV / 64, NQ / 64), 256, 0, stream>>>(
      key, val2, dotv, NQ, NV);
  // 5) sampler -> out1                            [1024,128]
  sample_kernel<<<NQ / 2, 256, 0, stream>>>(dotv, off_out, aw_out, ref3d, out1);
  // 6) out = out1 @ W_o + b_o + query             [1024,128]
  gemm_nn_k128<<<dim3(128 / 64, NQ / 64), 256, 0, stream>>>(
      out1, W_o, b_o, query, out, NQ, 128);
}

// Round 3
// 114.088 us; speedup vs baseline: 1.0725x; 1.0725x over previous
//
#include <hip/hip_runtime.h>
#include <hip/hip_bf16.h>

// UVCrossAttention — MI355X (gfx950), Round 3.
//
// Algebra: dotv[q,v] = key[q]·(value[v]@W_v + b_v)
//                    = (key@W_v^T)[q]·value[v] + key[q]·b_v
// so keyp = key@W_v^T depends only on inputs -> all "phase 1" GEMMs
// (off, aw, keyp, c) run in ONE dispatch. Final @W_o + query is fused into
// the sampler (each block owns its 2 queries' full out1 rows).
//
// 3 dispatches: p1 (off|aw|keyp|c) -> p2 (dotv NT GEMM) -> p3 (sample+out).
// R3 fix: keyp is 1024x128 = 32 tiles (R2 launched only 16 -> rows 512+
// poisoned -> absmax 0.30).

#define NQ   1024
#define NV   1024
#define ND   128
#define NP   4
#define IMG_W 32
#define IMG_H 32

// ---------------------------------------------------------------------------
// 64x64 tile GEMM, K=128 fully staged, A staged TRANSPOSED (sA[e][m]) so the
// inner loop is 2x ds_read_b128 + 16 FMA. B operand either NN ([128][N]) or
// NT ([N][128]). 256 threads, 4x4 micro-tile. LDS = 64 KB -> 2 blocks/CU.
// ---------------------------------------------------------------------------
__device__ __forceinline__ void gemm_tile64(
    const float* __restrict__ A,      // [M][128] row-major
    const float* __restrict__ B,      // NN: [128][N]; NT: [N][128]
    int N, bool nt,
    const float* __restrict__ bias,   // [N] or null
    const float* __restrict__ cvec,   // [M] or null (added to every col)
    float* __restrict__ C,            // [M][N]
    int m0, int n0, float* sA, float* sB) {
  const int tid = threadIdx.x;

  // stage A transposed: sA[e*64 + m]. Lanes write consecutive m -> 2-way (free).
#pragma unroll
  for (int k = 0; k < 8; ++k) {
    int c = tid + k * 256;
    int m = c & 63, e4 = c >> 6;
    const float4 v = *(const float4*)(A + (size_t)(m0 + m) * 128 + e4 * 4);
    sA[(e4 * 4 + 0) * 64 + m] = v.x;
    sA[(e4 * 4 + 1) * 64 + m] = v.y;
    sA[(e4 * 4 + 2) * 64 + m] = v.z;
    sA[(e4 * 4 + 3) * 64 + m] = v.w;
  }
  if (nt) {
    // Bt[n][e] -> sB[e*64 + n], same transpose pattern as A
#pragma unroll
    for (int k = 0; k < 8; ++k) {
      int c = tid + k * 256;
      int n = c & 63, e4 = c >> 6;
      const float4 v = *(const float4*)(B + (size_t)(n0 + n) * 128 + e4 * 4);
      sB[(e4 * 4 + 0) * 64 + n] = v.x;
      sB[(e4 * 4 + 1) * 64 + n] = v.y;
      sB[(e4 * 4 + 2) * 64 + n] = v.z;
      sB[(e4 * 4 + 3) * 64 + n] = v.w;
    }
  } else {
    // B[e][n] -> sB[e*64 + n], coalesced float4 global reads
#pragma unroll
    for (int k = 0; k < 8; ++k) {
      int c = tid + k * 256;
      int n4 = c & 15, e = c >> 4;
      *(float4*)(sB + e * 64 + n4 * 4) =
          *(const float4*)(B + (size_t)e * N + n0 + n4 * 4);
    }
  }
  __syncthreads();

  const int tx = tid & 15, ty = tid >> 4;
  float acc[4][4] = {};
#pragma unroll 8
  for (int e = 0; e < 128; ++e) {
    const float4 a = *(const float4*)(sA + e * 64 + ty * 4);  // broadcast-friendly
    const float4 b = *(const float4*)(sB + e * 64 + tx * 4);  // 2-way (free)
    acc[0][0] += a.x * b.x; acc[0][1] += a.x * b.y; acc[0][2] += a.x * b.z; acc[0][3] += a.x * b.w;
    acc[1][0] += a.y * b.x; acc[1][1] += a.y * b.y; acc[1][2] += a.y * b.z; acc[1][3] += a.y * b.w;
    acc[2][0] += a.z * b.x; acc[2][1] += a.z * b.y; acc[2][2] += a.z * b.z; acc[2][3] += a.z * b.w;
    acc[3][0] += a.w * b.x; acc[3][1] += a.w * b.y; acc[3][2] += a.w * b.z; acc[3][3] += a.w * b.w;
  }

  float4 bv = make_float4(0.f, 0.f, 0.f, 0.f);
  if (bias) bv = *(const float4*)(bias + n0 + tx * 4);
#pragma unroll
  for (int i = 0; i < 4; ++i) {
    const int m = m0 + ty * 4 + i;
    float cv = cvec ? cvec[m] : 0.f;
    float4 r;
    r.x = acc[i][0] + bv.x + cv;
    r.y = acc[i][1] + bv.y + cv;
    r.z = acc[i][2] + bv.z + cv;
    r.w = acc[i][3] + bv.w + cv;
    *(float4*)(C + (size_t)m * N + n0 + tx * 4) = r;
  }
}

// ---------------------------------------------------------------------------
// p1: off = query@W_off+b_off (256 tiles) | aw = query@W_attn+b_attn (128)
//     keyp = key@W_v^T (32 tiles, NT) | c[q] = key[q].b_v (1 block)
// ---------------------------------------------------------------------------
__global__ __launch_bounds__(256, 2) void p1_kernel(
    const float* __restrict__ query, const float* __restrict__ key,
    const float* __restrict__ W_off, const float* __restrict__ b_off,
    const float* __restrict__ W_attn, const float* __restrict__ b_attn,
    const float* __restrict__ W_v, const float* __restrict__ b_v,
    float* __restrict__ off_ws, float* __restrict__ aw_ws,
    float* __restrict__ keyp_ws, float* __restrict__ c_ws) {
  __shared__ float sA[128 * 64];
  __shared__ float sB[128 * 64];
  const int t = blockIdx.x;
  if (t < 256) {
    gemm_tile64(query, W_off, 1024, false, b_off, nullptr, off_ws,
                (t >> 4) * 64, (t & 15) * 64, sA, sB);
  } else if (t < 384) {
    const int u = t - 256;
    gemm_tile64(query, W_attn, 512, false, b_attn, nullptr, aw_ws,
                (u >> 3) * 64, (u & 7) * 64, sA, sB);
  } else if (t < 416) {
    const int u = t - 384;                 // 32 tiles: 16 m x 2 n
    gemm_tile64(key, W_v, 128, true, nullptr, nullptr, keyp_ws,
                (u >> 1) * 64, (u & 1) * 64, sA, sB);
  } else {
    // c[q] = key[q] . b_v   (b_v == 0 in this problem, kept for generality)
    for (int i = 0; i < 4; ++i) {
      const int q = threadIdx.x + i * 256;
      float s = 0.f;
      for (int e = 0; e < 128; ++e) s += key[(size_t)q * 128 + e] * b_v[e];
      c_ws[q] = s;
    }
  }
}

// ---------------------------------------------------------------------------
// p2: dotv = keyp @ value^T + c[m]   (NT, 256 tiles)
// ---------------------------------------------------------------------------
__global__ __launch_bounds__(256, 2) void p2_kernel(
    const float* __restrict__ keyp_ws, const float* __restrict__ value,
    const float* __restrict__ c_ws, float* __restrict__ dotv_ws) {
  __shared__ float sA[128 * 64];
  __shared__ float sB[128 * 64];
  const int t = blockIdx.x;
  gemm_tile64(keyp_ws, value, 1024, true, nullptr, c_ws, dotv_ws,
              (t >> 4) * 64, (t & 15) * 64, sA, sB);
}

// ---------------------------------------------------------------------------
// p3: per 2 queries: stage dotv rows as 32x32 images in LDS; per (q,d):
// softmax over 4 points, 4 bilinear samples, out1 to LDS; then fused
// out = out1 @ W_o + b_o + query.
// ---------------------------------------------------------------------------
__global__ __launch_bounds__(256) void p3_kernel(
    const float* __restrict__ dotv,    // [NQ][NV]
    const float* __restrict__ off,     // [NQ][1024]
    const float* __restrict__ awr,     // [NQ][512]
    const float* __restrict__ ref3d,   // [NQ*ND][2]
    const float* __restrict__ query,   // [NQ][128]
    const float* __restrict__ W_o,     // [128][128]
    const float* __restrict__ b_o,     // [128]
    float* __restrict__ out) {         // [NQ][128]
  __shared__ float img[2][NV];
  __shared__ float o1s[2][ND];

  const int tid = threadIdx.x;
  const int q0 = blockIdx.x * 2;

#pragma unroll
  for (int k = 0; k < 2; ++k) {
    int c = tid + k * 256;
    int qq = c >> 8, v4 = c & 255;
    *(float4*)(&img[qq][v4 * 4]) =
        *(const float4*)(dotv + (size_t)(q0 + qq) * NV + v4 * 4);
  }
  __syncthreads();

  {
    const int qq = tid >> 7;
    const int q = q0 + qq;
    const int d = tid & 127;
    const float* im = img[qq];
    const size_t qe = (size_t)q * ND + d;

    const float rx = ref3d[qe * 2 + 0];
    const float ry = ref3d[qe * 2 + 1];

    const float* awp = awr + (size_t)q * (ND * NP) + d * NP;
    const float a0 = awp[0], a1 = awp[1], a2 = awp[2], a3 = awp[3];
    const float mx = fmaxf(fmaxf(a0, a1), fmaxf(a2, a3));
    const float e0 = __expf(a0 - mx), e1 = __expf(a1 - mx),
                e2 = __expf(a2 - mx), e3 = __expf(a3 - mx);
    const float inv = 1.0f / (e0 + e1 + e2 + e3);
    const float w[4] = {e0 * inv, e1 * inv, e2 * inv, e3 * inv};

    const float* op = off + (size_t)q * (ND * NP * 2) + d * (NP * 2);

    float acc = 0.0f;
#pragma unroll
    for (int p = 0; p < NP; ++p) {
      const float x = rx * (float)IMG_W + op[p * 2 + 0] - 0.5f;
      const float y = ry * (float)IMG_H + op[p * 2 + 1] - 0.5f;
      const float xf = floorf(x), yf = floorf(y);
      const int ix0 = (int)xf, iy0 = (int)yf;
      const float wx1 = x - xf, wy1 = y - yf;
      const float wx0 = 1.0f - wx1, wy0 = 1.0f - wy1;

      float s = 0.0f;
#pragma unroll
      for (int cy = 0; cy < 2; ++cy) {
#pragma unroll
        for (int cx = 0; cx < 2; ++cx) {
          const int ix = ix0 + cx, iy = iy0 + cy;
          const bool valid = (ix >= 0) & (ix < IMG_W) & (iy >= 0) & (iy < IMG_H);
          const int cix = min(max(ix, 0), IMG_W - 1);
          const int ciy = min(max(iy, 0), IMG_H - 1);
          const float wgt = (cx ? wx1 : wx0) * (cy ? wy1 : wy0);
          s += valid ? im[ciy * IMG_W + cix] * wgt : 0.0f;
        }
      }
      acc += w[p] * s;
    }
    o1s[qq][d] = acc * (1.0f / 128.0f);
  }
  __syncthreads();

  // fused output GEMM: out[q][n] = sum_d o1s[q][d]*W_o[d][n] + b_o[n] + query[q][n]
  {
    const int qq = tid >> 7;
    const int q = q0 + qq;
    const int n = tid & 127;
    float acc = b_o[n] + query[(size_t)q * 128 + n];
#pragma unroll 8
    for (int d = 0; d < 128; ++d)
      acc += o1s[qq][d] * W_o[(size_t)d * 128 + n];  // coalesced across lanes
    out[(size_t)q * 128 + n] = acc;
  }
}

// ---------------------------------------------------------------------------
extern "C" void kernel_launch(void* const* d_in, const int* in_sizes, int n_in,
                              void* d_out, int out_size, void* d_ws, size_t ws_size,
                              hipStream_t stream) {
  const float* query  = (const float*)d_in[0];
  const float* key    = (const float*)d_in[1];
  const float* value  = (const float*)d_in[2];
  const float* ref3d  = (const float*)d_in[3];
  // d_in[4] = spatial_shapes [[32,32]] (hardcoded)
  const float* W_off  = (const float*)d_in[5];
  const float* b_off  = (const float*)d_in[6];
  const float* W_attn = (const float*)d_in[7];
  const float* b_attn = (const float*)d_in[8];
  const float* W_v    = (const float*)d_in[9];
  const float* b_v    = (const float*)d_in[10];
  const float* W_o    = (const float*)d_in[11];
  const float* b_o    = (const float*)d_in[12];
  float* out = (float*)d_out;

  float* ws = (float*)d_ws;
  float* off_ws  = ws;                             // 1024*1024
  float* aw_ws   = off_ws + (size_t)NQ * 1024;     // 1024*512
  float* keyp_ws = aw_ws + (size_t)NQ * 512;       // 1024*128
  float* c_ws    = keyp_ws + (size_t)NQ * 128;     // 1024
  float* dotv_ws = c_ws + 1024;                    // 1024*1024

  p1_kernel<<<417, 256, 0, stream>>>(query, key, W_off, b_off, W_attn, b_attn,
                                     W_v, b_v, off_ws, aw_ws, keyp_ws, c_ws);
  p2_kernel<<<256, 256, 0, stream>>>(keyp_ws, value, c_ws, dotv_ws);
  p3_kernel<<<512, 256, 0, stream>>>(dotv_ws, off_ws, aw_ws, ref3d, query,
                                     W_o, b_o, out);
}